// Round 6
// baseline (399.007 us; speedup 1.0000x reference)
//
#include <hip/hip_runtime.h>
#include <hip/hip_bf16.h>
#include <math.h>

#define G_HID 16
#define S_HID 10
#define D 128
#define MAX_STEP 4
#define NEG 0.01f
#define SCAN_TILE 1024
#define YT_PITCH 168   // LDS transpose pitch (bf16 elems): 84 words % 32 = 20 -> 2-way banks

typedef __attribute__((ext_vector_type(8))) short short8;
typedef __attribute__((ext_vector_type(4))) float f32x4;

__device__ __forceinline__ float leaky_f(float v){ return v >= 0.f ? v : NEG*v; }
__device__ __forceinline__ unsigned short f2bf(float f){
    unsigned int u = __float_as_uint(f);
    u = (u + 0x7FFFu + ((u>>16)&1u)) >> 16;
    return (unsigned short)u;
}
__device__ __forceinline__ float bf_lo(unsigned int v){ return __uint_as_float(v << 16); }
__device__ __forceinline__ float bf_hi(unsigned int v){ return __uint_as_float(v & 0xFFFF0000u); }
__device__ __forceinline__ float bfu(unsigned short u){ return __uint_as_float(((unsigned int)u) << 16); }

// ---------------- prep: A, A^2, A^3 (f32) + zpack of z0 (MFMA A-frag layout) ----------------
__global__ void prep_kernel(const float* __restrict__ hidden_adj,   // [16][45]
                            const float* __restrict__ hidden_feat,  // [16][10][128]
                            short* __restrict__ zpack,              // [10][4][64][8]
                            float* __restrict__ Ai)                 // [3][16][10][10]
{
    int g = blockIdx.x;
    __shared__ float Ag[S_HID][S_HID];
    __shared__ float A2[S_HID][S_HID];
    __shared__ float A3[S_HID][S_HID];
    int t = threadIdx.x;  // 128
    if (t < S_HID*S_HID) {
        int i = t / S_HID, j = t % S_HID;
        float v = 0.f;
        if (i < j) {
            int idx = 9*i - i*(i-1)/2 + (j - i - 1);
            v = leaky_f(hidden_adj[g*45 + idx]);
        } else if (i > j) {
            int idx = 9*j - j*(j-1)/2 + (i - j - 1);
            v = leaky_f(hidden_adj[g*45 + idx]);
        }
        Ag[i][j] = v;
    }
    __syncthreads();
    if (t < 100){
        int s = t/10, u = t%10;
        float c = 0.f;
        #pragma unroll
        for (int w = 0; w < 10; ++w) c += Ag[s][w]*Ag[w][u];
        A2[s][u] = c;
    }
    __syncthreads();
    if (t < 100){
        int s = t/10, u = t%10;
        float c = 0.f;
        #pragma unroll
        for (int w = 0; w < 10; ++w) c += A2[s][w]*Ag[w][u];
        A3[s][u] = c;
        Ai[0*1600 + g*100 + t] = Ag[s][u];
        Ai[1*1600 + g*100 + t] = A2[s][u];
        Ai[2*1600 + g*100 + t] = A3[s][u];
    }
    // zpack: rows g*10..g*10+9 of the 160-row A-operand
    for (int idx = t; idx < S_HID*D; idx += 128) {
        int s = idx / D, k = idx % D;
        int row = g*S_HID + s;
        int tt = row >> 4, li = row & 15;
        int kt = k >> 5, q = (k >> 3) & 3, j = k & 7;
        zpack[((tt*4 + kt)*64 + q*16 + li)*8 + j] = (short)f2bf(hidden_feat[(g*S_HID + s)*D + k]);
    }
}

// ---------------- pack fc_w into MFMA B-fragment layout ----------------
__global__ void wpack_kernel(const float* __restrict__ fc_w, short* __restrict__ wp){
    int idx = blockIdx.x*256 + threadIdx.x;
    if (idx >= 16384) return;
    int j = idx & 7, lane = (idx >> 3) & 63, ctkt = idx >> 9;
    int ct = ctkt & 7, kt = ctkt >> 3;
    int k   = kt*32 + (lane >> 4)*8 + j;
    int col = ct*16 + (lane & 15);
    wp[idx] = (short)f2bf(fc_w[k*D + col]);
}

// ---------------- CSR build ----------------
__global__ void count_kernel(const int* __restrict__ dst, int* __restrict__ offsets,
                             int* __restrict__ rnk, int E){
    int e = blockIdx.x*blockDim.x + threadIdx.x;
    if (e < E) rnk[e] = atomicAdd(&offsets[dst[e]+1], 1);
}

__global__ void scan1_kernel(int* __restrict__ data, int* __restrict__ bsums, int n){
    __shared__ int wsum[4];
    int base = blockIdx.x * SCAN_TILE + threadIdx.x*4;
    int v[4];
    #pragma unroll
    for (int j=0;j<4;++j) v[j] = (base+j < n) ? data[base+j] : 0;
    v[1]+=v[0]; v[2]+=v[1]; v[3]+=v[2];
    int lane = threadIdx.x & 63;
    int w = threadIdx.x >> 6;
    int s = v[3];
    for (int d=1; d<64; d<<=1){
        int o = __shfl_up(s, d);
        if (lane >= d) s += o;
    }
    if (lane == 63) wsum[w] = s;
    int sexc = s - v[3];
    __syncthreads();
    int woff = 0;
    for (int ww=0; ww<w; ++ww) woff += wsum[ww];
    int off = woff + sexc;
    #pragma unroll
    for (int j=0;j<4;++j) { if (base+j < n) data[base+j] = v[j] + off; }
    if (threadIdx.x == 255) bsums[blockIdx.x] = off + v[3];
}

__global__ void scan2_kernel(int* __restrict__ bsums, int nb){
    __shared__ int ws[4];
    __shared__ int carry_s;
    if (threadIdx.x == 0) carry_s = 0;
    __syncthreads();
    for (int start = 0; start < nb; start += 256){
        int i = start + (int)threadIdx.x;
        int v = (i < nb) ? bsums[i] : 0;
        int lane = threadIdx.x & 63, w = threadIdx.x >> 6;
        int s = v;
        for (int d=1; d<64; d<<=1){ int o = __shfl_up(s, d); if (lane >= d) s += o; }
        if (lane == 63) ws[w] = s;
        __syncthreads();
        int woff = 0;
        for (int ww=0; ww<w; ++ww) woff += ws[ww];
        int inc = s + woff + carry_s;
        if (i < nb) bsums[i] = inc - v;
        __syncthreads();
        if (threadIdx.x == 255) carry_s = inc;
        __syncthreads();
    }
}

__global__ void scan3_kernel(int* __restrict__ data, const int* __restrict__ bsums, int n){
    int base = blockIdx.x * SCAN_TILE + threadIdx.x*4;
    int add = bsums[blockIdx.x];
    #pragma unroll
    for (int j=0;j<4;++j){ if (base+j < n) data[base+j] += add; }
}

__global__ void fill_kernel(const int* __restrict__ src, const int* __restrict__ dst,
                            const int* __restrict__ rnk, const int* __restrict__ offsets,
                            int* __restrict__ csr, int E){
    int e = blockIdx.x*blockDim.x + threadIdx.x;
    if (e < E) csr[offsets[dst[e]] + rnk[e]] = src[e];
}

// ======== helpers ========
__device__ __forceinline__ void compute_slots(const int* __restrict__ batch, int n0, int N,
                                              int* slots, int* slotb, int* nslots_s, int t){
    if (t < 64) {
        int gn = n0 + t;
        int b = (gn < N) ? batch[gn] : -1;
        int bprev = -1;
        if (t > 0) bprev = (gn-1 < N) ? batch[gn-1] : -1;
        int flag = (t == 0 || b != bprev) ? 1 : 0;
        int s = flag;
        for (int d=1; d<64; d<<=1){ int o = __shfl_up(s, d); if (t >= d) s += o; }
        int slot = s - 1;
        slots[t] = slot;
        if (flag) slotb[slot] = b;
        if (t == 63) *nslots_s = s;
    }
}

// ---------------- fused: embed gather + fc MFMA + sigmoid + Y0 + self-dot + W0 write ----------------
__global__ __launch_bounds__(256) void embed_step0_kernel(
        const int* __restrict__ x_idx, const float* __restrict__ poi_emb,
        const short* __restrict__ wp, const float* __restrict__ fc_b,
        const short* __restrict__ zpack, const int* __restrict__ batch,
        unsigned short* __restrict__ W0,   // [N][160] bf16
        float* __restrict__ pooled, int N)
{
    __shared__ __align__(16) char lbuf[64*YT_PITCH*2];  // xs[64][136] bf16, then ytr[64][168]
    __shared__ float accs[64][G_HID];
    __shared__ int slots[64];
    __shared__ int slotb[64];
    __shared__ int nslots_s;
    unsigned short* xs  = (unsigned short*)lbuf;
    unsigned short* ytr = (unsigned short*)lbuf;
    int n0 = blockIdx.x * 64;
    int t = threadIdx.x;  // 256

    #pragma unroll
    for (int i = 0; i < 8; ++i) {
        int idx = t + i*256;
        int row = idx >> 5, c4 = (idx & 31)*4;
        int gn = n0 + row;
        float4 v = make_float4(0.f,0.f,0.f,0.f);
        if (gn < N) v = *reinterpret_cast<const float4*>(&poi_emb[(size_t)x_idx[gn]*D + c4]);
        unsigned int p0 = (unsigned int)f2bf(v.x) | ((unsigned int)f2bf(v.y) << 16);
        unsigned int p1 = (unsigned int)f2bf(v.z) | ((unsigned int)f2bf(v.w) << 16);
        *reinterpret_cast<uint2*>(&xs[row*136 + c4]) = make_uint2(p0, p1);
    }
    for (int idx = t; idx < 64*G_HID; idx += 256) ((float*)accs)[idx] = 0.f;
    compute_slots(batch, n0, N, slots, slotb, &nslots_s, t);
    __syncthreads();

    int l = t & 63, w = t >> 6, li = l & 15, q = l >> 4;
    // fc layer
    short8 a[4];
    #pragma unroll
    for (int kt = 0; kt < 4; ++kt)
        a[kt] = *reinterpret_cast<const short8*>(&xs[(w*16 + li)*136 + kt*32 + q*8]);
    f32x4 facc[8];
    #pragma unroll
    for (int ct = 0; ct < 8; ++ct) facc[ct] = (f32x4){0.f,0.f,0.f,0.f};
    #pragma unroll
    for (int kt = 0; kt < 4; ++kt){
        #pragma unroll
        for (int ct = 0; ct < 8; ++ct){
            short8 b = reinterpret_cast<const short8*>(wp)[(kt*8 + ct)*64 + l];
            facc[ct] = __builtin_amdgcn_mfma_f32_16x16x32_bf16(a[kt], b, facc[ct], 0, 0, 0);
        }
    }
    #pragma unroll
    for (int ct = 0; ct < 8; ++ct){
        float bias = fc_b[ct*16 + li];
        #pragma unroll
        for (int r = 0; r < 4; ++r){
            int row = w*16 + q*4 + r;
            float s = (n0 + row < N) ? 1.f/(1.f + __expf(-(facc[ct][r] + bias))) : 0.f;
            xs[row*136 + ct*16 + li] = f2bf(s);
        }
    }
    __syncthreads();
    // B-frags (x) into registers; afterwards lbuf is reused as ytr
    short8 bw[4];
    #pragma unroll
    for (int kt = 0; kt < 4; ++kt)
        bw[kt] = *reinterpret_cast<const short8*>(&xs[(w*16 + li)*136 + kt*32 + q*8]);
    __syncthreads();

    // Y0 = Z0 X^T : 10 row-tiles of 16; write transposed bf16 into ytr[node][row]
    #pragma unroll
    for (int t10 = 0; t10 < 10; ++t10){
        f32x4 acc = (f32x4){0.f,0.f,0.f,0.f};
        #pragma unroll
        for (int kt = 0; kt < 4; ++kt){
            short8 az = *reinterpret_cast<const short8*>(&zpack[((t10*4 + kt)*64 + l)*8]);
            acc = __builtin_amdgcn_mfma_f32_16x16x32_bf16(az, bw[kt], acc, 0, 0, 0);
        }
        uint2 pk;
        pk.x = (unsigned int)f2bf(acc[0]) | ((unsigned int)f2bf(acc[1]) << 16);
        pk.y = (unsigned int)f2bf(acc[2]) | ((unsigned int)f2bf(acc[3]) << 16);
        *reinterpret_cast<uint2*>(&ytr[(w*16 + li)*YT_PITCH + t10*16 + q*4]) = pk;
    }
    __syncthreads();

    // W0 write: thread -> (node, quarter-row), 10 uint2 each, coalesced
    {
        int nd = t >> 2, part = t & 3, gn = n0 + nd;
        if (gn < N){
            const uint2* srcl = reinterpret_cast<const uint2*>(&ytr[nd*YT_PITCH + part*40]);
            uint2* dstg = reinterpret_cast<uint2*>(&W0[(size_t)gn*160 + part*40]);
            #pragma unroll
            for (int k2 = 0; k2 < 10; ++k2) dstg[k2] = srcl[k2];
        }
    }
    // self-dot d0[g,node] = sum_s Y0^2 -> slot pooling
    #pragma unroll
    for (int i = 0; i < 4; ++i){
        int nd2 = t & 63;
        int g = (t >> 6) + i*4;
        if (n0 + nd2 < N){
            float c = 0.f;
            #pragma unroll
            for (int s = 0; s < S_HID; ++s){
                float y = bfu(ytr[nd2*YT_PITCH + g*10 + s]);
                c += y*y;
            }
            atomicAdd(&accs[slots[nd2]][g], c);
        }
    }
    __syncthreads();
    int ns = nslots_s;
    for (int idx = t; idx < ns*G_HID; idx += 256){
        int j = idx >> 4, g = idx & 15;
        int b = slotb[j];
        if (b >= 0) atomicAdd(&pooled[(size_t)b*64 + g], accs[j][g]);
    }
}

// ---------------- per-step fused: W_i = prop(W_{i-1}); d = <A^i Y0, W_i>; pool ----------------
__global__ __launch_bounds__(256) void propw_kernel(
        const uint2* __restrict__ Win, uint2* __restrict__ Wout,
        const uint2* __restrict__ Y0,
        const int* __restrict__ offsets, const int* __restrict__ csr,
        const float* __restrict__ Ai_g,          // [16][10][10] for this step
        const int* __restrict__ batch, float* __restrict__ pooled,
        int N, int stepoff)
{
    __shared__ float Aw[1600];
    __shared__ float ylds[4][160];
    __shared__ float gacc[4][16];
    int t = threadIdx.x;
    for (int idx = t; idx < 1600; idx += 256) Aw[idx] = Ai_g[idx];
    __syncthreads();

    int wv = t >> 6, l = t & 63;
    int v = blockIdx.x*4 + wv;
    if (v >= N) return;   // no block-wide barriers after this point

    int beg = offsets[v], end = offsets[v+1];
    float a0=0.f, a1=0.f, a2=0.f, a3=0.f;
    for (int base = beg; base < end; base += 64){
        int cnt = min(64, end - base);
        int myu = (base + l < end) ? csr[base + l] : 0;
        int ei = 0;
        for (; ei + 4 <= cnt; ei += 4){
            int u0 = __shfl(myu, ei), u1 = __shfl(myu, ei+1);
            int u2 = __shfl(myu, ei+2), u3 = __shfl(myu, ei+3);
            uint2 w0 = make_uint2(0,0), w1 = w0, w2 = w0, w3 = w0;
            if (l < 40){
                w0 = Win[(size_t)u0*40 + l];
                w1 = Win[(size_t)u1*40 + l];
                w2 = Win[(size_t)u2*40 + l];
                w3 = Win[(size_t)u3*40 + l];
            }
            a0 += bf_lo(w0.x) + bf_lo(w1.x) + bf_lo(w2.x) + bf_lo(w3.x);
            a1 += bf_hi(w0.x) + bf_hi(w1.x) + bf_hi(w2.x) + bf_hi(w3.x);
            a2 += bf_lo(w0.y) + bf_lo(w1.y) + bf_lo(w2.y) + bf_lo(w3.y);
            a3 += bf_hi(w0.y) + bf_hi(w1.y) + bf_hi(w2.y) + bf_hi(w3.y);
        }
        for (; ei < cnt; ++ei){
            int u = __shfl(myu, ei);
            uint2 wv2 = make_uint2(0,0);
            if (l < 40) wv2 = Win[(size_t)u*40 + l];
            a0 += bf_lo(wv2.x); a1 += bf_hi(wv2.x);
            a2 += bf_lo(wv2.y); a3 += bf_hi(wv2.y);
        }
    }
    // write W_i, load Y0 row into LDS (f32)
    if (l < 40){
        uint2 o;
        o.x = (unsigned int)f2bf(a0) | ((unsigned int)f2bf(a1) << 16);
        o.y = (unsigned int)f2bf(a2) | ((unsigned int)f2bf(a3) << 16);
        Wout[(size_t)v*40 + l] = o;
        uint2 y = Y0[(size_t)v*40 + l];
        float4 yf;
        yf.x = bf_lo(y.x); yf.y = bf_hi(y.x); yf.z = bf_lo(y.y); yf.w = bf_hi(y.y);
        *reinterpret_cast<float4*>(&ylds[wv][l*4]) = yf;
    }
    if (l < 16) gacc[wv][l] = 0.f;
    __threadfence_block();   // intra-wave LDS ordering (no barrier: waves may have returned)

    if (l < 40){
        float aj[4] = {a0, a1, a2, a3};
        int idx0 = 4*l;
        int ga = idx0/10, gb = (idx0+3)/10;
        float c0 = 0.f, c1 = 0.f;
        #pragma unroll
        for (int j = 0; j < 4; ++j){
            int idx = idx0 + j;
            int g = idx/10, s = idx - g*10;
            float u0v = 0.f;
            #pragma unroll
            for (int tt = 0; tt < 10; ++tt)
                u0v += Aw[g*100 + s*10 + tt] * ylds[wv][g*10 + tt];
            float p = u0v * aj[j];
            if (g == ga) c0 += p; else c1 += p;
        }
        atomicAdd(&gacc[wv][ga], c0);
        if (gb != ga) atomicAdd(&gacc[wv][gb], c1);
    }
    __threadfence_block();
    if (l < 16){
        int b = batch[v];
        atomicAdd(&pooled[(size_t)b*64 + stepoff + l], gacc[wv][l]);
    }
}

// ---------------- out = leaky(pooled @ mlp_w + mlp_b) ----------------
__global__ void out_kernel(const float* __restrict__ pooled, const float* __restrict__ mlp_w,
                           const float* __restrict__ mlp_b, float* __restrict__ out, int B){
    __shared__ float row[64];
    int b = blockIdx.x;
    int t = threadIdx.x;  // 128
    if (t < 64) row[t] = pooled[(size_t)b*64 + t];
    __syncthreads();
    float acc = mlp_b[t];
    for (int j=0;j<64;++j) acc += row[j]*mlp_w[j*D + t];
    out[(size_t)b*D + t] = leaky_f(acc);
}

extern "C" void kernel_launch(void* const* d_in, const int* in_sizes, int n_in,
                              void* d_out, int out_size, void* d_ws, size_t ws_size,
                              hipStream_t stream)
{
    const int*   x_idx = (const int*)d_in[0];
    const int*   edge  = (const int*)d_in[1];
    const int*   batch = (const int*)d_in[2];
    const float* poi   = (const float*)d_in[3];
    const float* fc_w  = (const float*)d_in[4];
    const float* fc_b  = (const float*)d_in[5];
    const float* adj   = (const float*)d_in[6];
    const float* feat  = (const float*)d_in[7];
    const float* mlp_w = (const float*)d_in[8];
    const float* mlp_b = (const float*)d_in[9];
    float* out = (float*)d_out;

    int N = in_sizes[0];
    int E = in_sizes[1] / 2;
    int B = out_size / D;
    int sblk = (N + 63) / 64;
    size_t NP = (size_t)sblk * 64;

    char* p = (char*)d_ws;
    auto alloc = [&](size_t bytes)->char* {
        char* r = p;
        p += (bytes + 255) & ~(size_t)255;
        return r;
    };
    unsigned short* Y0 = (unsigned short*)alloc(NP*160*2);
    unsigned short* Wa = (unsigned short*)alloc(NP*160*2);
    unsigned short* Wb = (unsigned short*)alloc(NP*160*2);
    float* pooled      = (float*)alloc((size_t)B*64*4);
    short* zpack       = (short*)alloc((size_t)20480*2);
    short* wp          = (short*)alloc((size_t)16384*2);
    float* Ai          = (float*)alloc((size_t)3*1600*4);
    int*   offsets     = (int*)alloc((size_t)(N+1)*4);
    int*   rnk         = (int*)alloc((size_t)E*4);
    int*   csr         = (int*)alloc((size_t)E*4);
    int*   bsums       = (int*)alloc(4096);

    const int* srcp = edge;
    const int* dstp = edge + E;

    hipMemsetAsync(offsets, 0, (size_t)(N+1)*4, stream);
    hipMemsetAsync(pooled, 0, (size_t)B*64*4, stream);

    prep_kernel<<<G_HID, 128, 0, stream>>>(adj, feat, zpack, Ai);
    wpack_kernel<<<64, 256, 0, stream>>>(fc_w, wp);

    count_kernel<<<(E+255)/256, 256, 0, stream>>>(dstp, offsets, rnk, E);
    int scan_n = N + 1;
    int nblk = (scan_n + SCAN_TILE - 1) / SCAN_TILE;
    scan1_kernel<<<nblk, 256, 0, stream>>>(offsets, bsums, scan_n);
    scan2_kernel<<<1, 256, 0, stream>>>(bsums, nblk);
    scan3_kernel<<<nblk, 256, 0, stream>>>(offsets, bsums, scan_n);
    fill_kernel<<<(E+255)/256, 256, 0, stream>>>(srcp, dstp, rnk, offsets, csr, E);

    embed_step0_kernel<<<sblk, 256, 0, stream>>>(x_idx, poi, wp, fc_b, zpack, batch,
                                                 Y0, pooled, N);

    const unsigned short* win = Y0;
    unsigned short* bufs[2] = {Wa, Wb};
    for (int i = 1; i < MAX_STEP; ++i){
        unsigned short* wout = bufs[(i-1) & 1];
        propw_kernel<<<(N+3)/4, 256, 0, stream>>>(
            (const uint2*)win, (uint2*)wout, (const uint2*)Y0,
            offsets, csr, Ai + (size_t)(i-1)*1600, batch, pooled, N, i*G_HID);
        win = wout;
    }
    out_kernel<<<B, D, 0, stream>>>(pooled, mlp_w, mlp_b, out, B);
}